// Round 4
// baseline (83.525 us; speedup 1.0000x reference)
//
#include <hip/hip_runtime.h>

#define B_IMG 16
#define A_N   65536
#define M_N   64
#define BLK   256
#define APT   8                                   // anchors per thread
#define BLOCKS_PER_IMG (A_N / (BLK * APT))        // 32
#define NBLOCKS (B_IMG * BLOCKS_PER_IMG)          // 512
#define NBINS 160                                 // 64-unit bins over [0, 10240)
#define INV_BINW (1.0f / 64.0f)
#define MARGIN 30.5f                              // gw/2 < 30 (+0.5 rounding slack)

// ws layout: float img_acc[B_IMG][2] (sum, cnt) at 0; int counter at 128 B.
// Fused kernel: bin 64 boxes -> CSR in LDS; each anchor scans only candidate
// boxes (center within +-MARGIN of its span — superset of overlapping boxes,
// exact since skipped boxes have iou=0). Block partials go to per-image
// device atomics; the last block to finish normalizes and writes the mean.
__global__ __launch_bounds__(256) void rl_fused(
    const float* __restrict__ reg,       // (B, A, 2)
    const float2* __restrict__ anchors,  // (A) as float2
    const float* __restrict__ ann,       // (B, M, 3)
    float* __restrict__ img_acc,         // [B][2]
    int* __restrict__ counter,
    float* __restrict__ out)
{
    __shared__ float4 sboxes[M_N];       // sorted by (bin, m): (b0, b1, area, 0)
    __shared__ int    soff[NBINS + 1];   // CSR offsets
    __shared__ int    sbin[M_N];
    __shared__ int    sdone;
    const int b   = blockIdx.y;
    const int bx  = blockIdx.x;
    const int tid = threadIdx.x;

    // Phase A (tid<64): bin assignment (invalid -> sentinel bin NBINS)
    float b0 = 0.f, b1 = 0.f;
    if (tid < M_N) {
        const float* p = ann + (b * M_N + tid) * 3;
        b0 = p[0]; b1 = p[1];
        float v = p[2];
        float gctr = b0 + 0.5f * (b1 - b0);
        int bin = (int)floorf(gctr * INV_BINW);
        bin = min(max(bin, 0), NBINS - 1);
        sbin[tid] = (v != -1.0f) ? bin : NBINS;
    }
    __syncthreads();

    // Phase B (tid<64, wave 0): stable rank-sort by (bin, m), scatter boxes.
    // Phase C (tid in [64, 64+NBINS], waves 1-3): CSR offsets — concurrent.
    if (tid < M_N) {
        const int mybin = sbin[tid];
        int rank = 0;
        #pragma unroll 8
        for (int m = 0; m < M_N; ++m) {
            int bm = sbin[m];
            rank += (bm < mybin) || (bm == mybin && m < tid);
        }
        sboxes[rank] = make_float4(b0, b1, b1 - b0, 0.0f);
    } else if (tid < 64 + NBINS + 1) {
        const int t = tid - 64;
        int cnt = 0;
        #pragma unroll 8
        for (int m = 0; m < M_N; ++m)
            cnt += (sbin[m] < t);
        soff[t] = cnt;
    }
    __syncthreads();

    const int abase = bx * (BLK * APT) + tid;
    float lsum = 0.0f, lcnt = 0.0f;

    #pragma unroll
    for (int j = 0; j < APT; ++j) {
        const float2 an = anchors[abase + j * BLK];
        const float ax = an.x, ay = an.y, aw = ay - ax;
        int lo = max((int)((ax - MARGIN) * INV_BINW), 0);
        int hi = min((int)((ay + MARGIN) * INV_BINW), NBINS - 1);
        int k    = soff[lo];
        const int kend = soff[hi + 1];

        float biw = 0.0f, bua = 1.0f;
        int   bidx = 0;
        for (; k < kend; ++k) {
            const float4 g = sboxes[k];
            float iw = fminf(ay, g.y) - fmaxf(ax, g.x);
            iw = fmaxf(iw, 0.0f);
            float ua = (aw + g.z) - iw;            // ua >= aw >= 20 > 0
            if (iw * bua > biw * ua) { biw = iw; bua = ua; bidx = k; }
        }

        if (biw >= 0.5f * bua) {                   // pos <=> iou >= 0.5
            lcnt += 1.0f;
            const float4 g = sboxes[bidx];
            float gw   = g.y - g.x;
            float gctr = g.x + 0.5f * gw;
            gw = fmaxf(gw, 1.0f);
            float actr = ax + 0.5f * aw;
            float tdx = (gctr - actr) / aw / 0.1f;
            float tdw = logf(gw / aw) / 0.2f;
            const float2 r = ((const float2*)reg)[(size_t)b * A_N + abase + j * BLK];
            float d0 = fabsf(tdx - r.x);
            float d1 = fabsf(tdw - r.y);
            const float third = 1.0f / 9.0f;
            lsum += (d0 <= third) ? 4.5f * d0 * d0 : d0 - (0.5f / 9.0f);
            lsum += (d1 <= third) ? 4.5f * d1 * d1 : d1 - (0.5f / 9.0f);
        }
    }

    // block reduction
    #pragma unroll
    for (int off = 32; off > 0; off >>= 1) {
        lsum += __shfl_down(lsum, off, 64);
        lcnt += __shfl_down(lcnt, off, 64);
    }
    __shared__ float rs[4], rc[4];
    const int wave = tid >> 6, lane = tid & 63;
    if (lane == 0) { rs[wave] = lsum; rc[wave] = lcnt; }
    __syncthreads();
    if (tid == 0) {
        float s = rs[0] + rs[1] + rs[2] + rs[3];
        float c = rc[0] + rc[1] + rc[2] + rc[3];
        atomicAdd(&img_acc[b * 2 + 0], s);
        atomicAdd(&img_acc[b * 2 + 1], c);
        __threadfence();                            // release partial sums
        int old = atomicAdd(counter, 1);
        sdone = (old == NBLOCKS - 1);
    }
    __syncthreads();

    // Last block finalizes: per-image normalize + mean over B.
    if (sdone) {
        float loss = 0.0f;
        if (tid < B_IMG) {
            float s = __hip_atomic_load(&img_acc[tid * 2 + 0],
                                        __ATOMIC_ACQUIRE, __HIP_MEMORY_SCOPE_AGENT);
            float c = __hip_atomic_load(&img_acc[tid * 2 + 1],
                                        __ATOMIC_ACQUIRE, __HIP_MEMORY_SCOPE_AGENT);
            loss = (c > 0.0f) ? s / (2.0f * fmaxf(c, 1.0f)) : 0.0f;
        }
        if (tid < 64) {
            #pragma unroll
            for (int off = 32; off > 0; off >>= 1)
                loss += __shfl_down(loss, off, 64);
            if (tid == 0) out[0] = loss * (1.0f / (float)B_IMG);
        }
    }
}

extern "C" void kernel_launch(void* const* d_in, const int* in_sizes, int n_in,
                              void* d_out, int out_size, void* d_ws, size_t ws_size,
                              hipStream_t stream)
{
    const float*  reg     = (const float*)d_in[0];   // (B, A, 2)
    const float2* anchors = (const float2*)d_in[1];  // (1, A, 2)
    const float*  ann     = (const float*)d_in[2];   // (B, M, 3)
    float* out = (float*)d_out;

    float* img_acc = (float*)d_ws;                   // 16 * 2 floats
    int*   counter = (int*)((char*)d_ws + 128);

    // d_ws is re-poisoned to 0xAA before every call — zero accumulators+counter.
    hipMemsetAsync(d_ws, 0, 132, stream);

    dim3 grid(BLOCKS_PER_IMG, B_IMG);
    rl_fused<<<grid, dim3(BLK), 0, stream>>>(reg, anchors, ann, img_acc, counter, out);
}

// Round 5
// 68.068 us; speedup vs baseline: 1.2271x; 1.2271x over previous
//
#include <hip/hip_runtime.h>

#define B_IMG 16
#define A_N   65536
#define M_N   64
#define BLK   256
#define APT   4                                   // anchors per thread (R3-proven best)
#define BLOCKS_PER_IMG (A_N / (BLK * APT))        // 64
#define NSLOT (B_IMG * BLOCKS_PER_IMG)            // 1024 partial slots
#define NBINS 160                                 // 64-unit bins over [0, 10240)
#define INV_BINW (1.0f / 64.0f)
#define MARGIN 30.5f                              // gw/2 < 30 (+0.5 rounding slack)

// Main kernel: bin the 64 boxes by center (CSR in LDS), each anchor scans only
// candidate boxes whose center lies within +-MARGIN of its span. Exact:
// skipped boxes have iw=0 -> iou=0, which can neither be pos nor beat a
// positive candidate; argmax index only matters when iou_max >= 0.5.
// NOTE (R4 post-mortem): do NOT fuse finalize via last-block-done — 512+
// device-scope atomics/fences on two hot cache lines cost ~15 us across
// 8 non-coherent XCD L2s. Contention-free partials + tiny 2nd kernel wins.
__global__ __launch_bounds__(256) void rl_main(
    const float* __restrict__ reg,       // (B, A, 2)
    const float2* __restrict__ anchors,  // (A) as float2
    const float* __restrict__ ann,       // (B, M, 3)
    float2* __restrict__ partials)       // [NSLOT]
{
    __shared__ float4 sboxes[M_N];       // sorted by (bin, m): (b0, b1, area, 0)
    __shared__ int    soff[NBINS + 1];   // CSR offsets
    __shared__ int    sbin[M_N];
    const int b   = blockIdx.y;
    const int bx  = blockIdx.x;
    const int tid = threadIdx.x;

    // Phase A (tid<64): bin assignment (invalid -> sentinel bin NBINS)
    float b0 = 0.f, b1 = 0.f;
    if (tid < M_N) {
        const float* p = ann + (b * M_N + tid) * 3;
        b0 = p[0]; b1 = p[1];
        float v = p[2];
        float gctr = b0 + 0.5f * (b1 - b0);
        int bin = (int)floorf(gctr * INV_BINW);
        bin = min(max(bin, 0), NBINS - 1);
        sbin[tid] = (v != -1.0f) ? bin : NBINS;
    }
    __syncthreads();

    // Phase B (wave 0): stable rank-sort by (bin, m), scatter boxes.
    // Phase C (waves 1-3): CSR offsets by direct counting — concurrent.
    if (tid < M_N) {
        const int mybin = sbin[tid];
        int rank = 0;
        #pragma unroll 8
        for (int m = 0; m < M_N; ++m) {
            int bm = sbin[m];
            rank += (bm < mybin) || (bm == mybin && m < tid);
        }
        sboxes[rank] = make_float4(b0, b1, b1 - b0, 0.0f);
    } else if (tid < 64 + NBINS + 1) {
        const int t = tid - 64;
        int cnt = 0;
        #pragma unroll 8
        for (int m = 0; m < M_N; ++m)
            cnt += (sbin[m] < t);
        soff[t] = cnt;
    }
    __syncthreads();

    const int abase = bx * (BLK * APT) + tid;

    // Batch all anchor loads up front so VMEM latency overlaps (ILP).
    float2 an[APT];
    #pragma unroll
    for (int j = 0; j < APT; ++j)
        an[j] = anchors[abase + j * BLK];

    float lsum = 0.0f, lcnt = 0.0f;
    #pragma unroll
    for (int j = 0; j < APT; ++j) {
        const float ax = an[j].x, ay = an[j].y, aw = ay - ax;
        int lo = max((int)((ax - MARGIN) * INV_BINW), 0);
        int hi = min((int)((ay + MARGIN) * INV_BINW), NBINS - 1);
        int k    = soff[lo];
        const int kend = soff[hi + 1];

        float biw = 0.0f, bua = 1.0f;
        int   bidx = 0;
        for (; k < kend; ++k) {
            const float4 g = sboxes[k];
            float iw = fminf(ay, g.y) - fmaxf(ax, g.x);
            iw = fmaxf(iw, 0.0f);
            float ua = (aw + g.z) - iw;            // ua >= aw >= 20 > 0
            if (iw * bua > biw * ua) { biw = iw; bua = ua; bidx = k; }
        }

        if (biw >= 0.5f * bua) {                   // pos <=> iou >= 0.5
            lcnt += 1.0f;
            const float4 g = sboxes[bidx];
            float gw   = g.y - g.x;
            float gctr = g.x + 0.5f * gw;
            gw = fmaxf(gw, 1.0f);
            float actr = ax + 0.5f * aw;
            float tdx = (gctr - actr) / aw / 0.1f;
            float tdw = logf(gw / aw) / 0.2f;
            const float2 r = ((const float2*)reg)[(size_t)b * A_N + abase + j * BLK];
            float d0 = fabsf(tdx - r.x);
            float d1 = fabsf(tdw - r.y);
            const float third = 1.0f / 9.0f;
            lsum += (d0 <= third) ? 4.5f * d0 * d0 : d0 - (0.5f / 9.0f);
            lsum += (d1 <= third) ? 4.5f * d1 * d1 : d1 - (0.5f / 9.0f);
        }
    }

    // wave reduction (64 lanes)
    #pragma unroll
    for (int off = 32; off > 0; off >>= 1) {
        lsum += __shfl_down(lsum, off, 64);
        lcnt += __shfl_down(lcnt, off, 64);
    }
    __shared__ float rs[4], rc[4];
    const int wave = tid >> 6, lane = tid & 63;
    if (lane == 0) { rs[wave] = lsum; rc[wave] = lcnt; }
    __syncthreads();
    if (tid == 0) {
        float s = rs[0] + rs[1] + rs[2] + rs[3];
        float c = rc[0] + rc[1] + rc[2] + rc[3];
        partials[b * BLOCKS_PER_IMG + bx] = make_float2(s, c);
    }
}

// Finalize: 16 waves, wave w reduces image w's 64 slots.
__global__ __launch_bounds__(1024) void rl_final_p(
    const float2* __restrict__ partials, float* __restrict__ out)
{
    __shared__ float simg[B_IMG];
    const int tid = threadIdx.x;
    const int w = tid >> 6, l = tid & 63;
    float2 p = partials[w * BLOCKS_PER_IMG + l];
    float s = p.x, c = p.y;
    #pragma unroll
    for (int off = 32; off > 0; off >>= 1) {
        s += __shfl_down(s, off, 64);
        c += __shfl_down(c, off, 64);
    }
    if (l == 0)
        simg[w] = (c > 0.0f) ? s / (2.0f * fmaxf(c, 1.0f)) : 0.0f;
    __syncthreads();
    if (tid == 0) {
        float t = 0.0f;
        #pragma unroll
        for (int i = 0; i < B_IMG; ++i) t += simg[i];
        out[0] = t * (1.0f / (float)B_IMG);
    }
}

// Finalize (atomic fallback for tiny ws): one wave.
__global__ void rl_final_a(const float* __restrict__ ws, float* __restrict__ out)
{
    const int tid = threadIdx.x;
    float loss = 0.0f;
    if (tid < B_IMG) {
        float s = ws[tid * 2 + 0], c = ws[tid * 2 + 1];
        loss = (c > 0.0f) ? s / (2.0f * fmaxf(c, 1.0f)) : 0.0f;
    }
    #pragma unroll
    for (int off = 32; off > 0; off >>= 1)
        loss += __shfl_down(loss, off, 64);
    if (tid == 0) out[0] = loss * (1.0f / (float)B_IMG);
}

// Fallback main (atomic mode) — only if ws is too small for partials.
__global__ __launch_bounds__(256) void rl_main_a(
    const float* __restrict__ reg, const float2* __restrict__ anchors,
    const float* __restrict__ ann, float* __restrict__ acc)
{
    // (unused in practice; minimal brute-force for safety)
    const int b = blockIdx.y, tid = threadIdx.x;
    const int a = blockIdx.x * BLK + tid;
    __shared__ float4 sbox[M_N];
    if (tid < M_N) {
        const float* p = ann + (b * M_N + tid) * 3;
        float b0 = p[0], b1 = p[1], v = p[2];
        if (v == -1.0f) { b0 = 3.0e5f; b1 = 3.0e5f; }
        sbox[tid] = make_float4(b0, b1, b1 - b0, 0.0f);
    }
    __syncthreads();
    float2 an = anchors[a];
    float ax = an.x, ay = an.y, aw = ay - ax;
    float biw = 0.0f, bua = 1.0f; int bidx = 0;
    for (int m = 0; m < M_N; ++m) {
        float4 g = sbox[m];
        float iw = fmaxf(fminf(ay, g.y) - fmaxf(ax, g.x), 0.0f);
        float ua = (aw + g.z) - iw;
        if (iw * bua > biw * ua) { biw = iw; bua = ua; bidx = m; }
    }
    float lsum = 0.0f, lcnt = 0.0f;
    if (biw >= 0.5f * bua) {
        lcnt = 1.0f;
        float4 g = sbox[bidx];
        float gw = g.y - g.x, gctr = g.x + 0.5f * gw;
        gw = fmaxf(gw, 1.0f);
        float actr = ax + 0.5f * aw;
        float tdx = (gctr - actr) / aw / 0.1f;
        float tdw = logf(gw / aw) / 0.2f;
        const float2 r = ((const float2*)reg)[(size_t)b * A_N + a];
        float d0 = fabsf(tdx - r.x), d1 = fabsf(tdw - r.y);
        const float third = 1.0f / 9.0f;
        lsum  = (d0 <= third) ? 4.5f * d0 * d0 : d0 - (0.5f / 9.0f);
        lsum += (d1 <= third) ? 4.5f * d1 * d1 : d1 - (0.5f / 9.0f);
    }
    #pragma unroll
    for (int off = 32; off > 0; off >>= 1) {
        lsum += __shfl_down(lsum, off, 64);
        lcnt += __shfl_down(lcnt, off, 64);
    }
    __shared__ float rs[4], rc[4];
    const int wave = tid >> 6, lane = tid & 63;
    if (lane == 0) { rs[wave] = lsum; rc[wave] = lcnt; }
    __syncthreads();
    if (tid == 0) {
        atomicAdd(&acc[b * 2 + 0], rs[0] + rs[1] + rs[2] + rs[3]);
        atomicAdd(&acc[b * 2 + 1], rc[0] + rc[1] + rc[2] + rc[3]);
    }
}

extern "C" void kernel_launch(void* const* d_in, const int* in_sizes, int n_in,
                              void* d_out, int out_size, void* d_ws, size_t ws_size,
                              hipStream_t stream)
{
    const float*  reg     = (const float*)d_in[0];   // (B, A, 2)
    const float2* anchors = (const float2*)d_in[1];  // (1, A, 2)
    const float*  ann     = (const float*)d_in[2];   // (B, M, 3)
    float* out = (float*)d_out;

    const size_t need = NSLOT * sizeof(float2);

    if (ws_size >= need) {
        float2* partials = (float2*)d_ws;   // every slot written -> no memset needed
        dim3 grid(BLOCKS_PER_IMG, B_IMG);
        rl_main<<<grid, dim3(BLK), 0, stream>>>(reg, anchors, ann, partials);
        rl_final_p<<<1, dim3(B_IMG * 64), 0, stream>>>(partials, out);
    } else {
        hipMemsetAsync(d_ws, 0, 2 * B_IMG * sizeof(float), stream);
        dim3 grid(A_N / BLK, B_IMG);
        rl_main_a<<<grid, dim3(BLK), 0, stream>>>(reg, anchors, ann, (float*)d_ws);
        rl_final_a<<<1, 64, 0, stream>>>((const float*)d_ws, out);
    }
}